// Round 2
// baseline (584.655 us; speedup 1.0000x reference)
//
#include <hip/hip_runtime.h>
#include <hip/hip_bf16.h>
#include <math.h>

// Shapes (fixed by the problem):
//   x      (4, 65536, 256) f32
//   style  (4, 512) f32
//   weight (1, 256, 256) f32  [c][o]
//   mod_w  (256, 512) f32
//   mod_b  (256,) f32
//   out    (4, 65536, 256) f32
#define IN_C   256
#define OUT_C  256
#define SDIM   512
#define NROWS  65536

constexpr float EPS       = 1e-8f;
constexpr float SCALE     = 0.0625f;               // 1/sqrt(256)
constexpr float MOD_SCALE = 0.04419417382415922f;  // 1/sqrt(512)

typedef __bf16 bf16x8 __attribute__((ext_vector_type(8)));
typedef float  f32x4  __attribute__((ext_vector_type(4)));

// ---------------------------------------------------------------------------
// Kernel 1: per-batch modulated + demodulated weight, stored TRANSPOSED
// wt[b][o][c] (bf16) so a GEMM B-fragment (8 consecutive k at fixed col o)
// is one contiguous 16B chunk.
// ---------------------------------------------------------------------------
__global__ __launch_bounds__(256) void modw_kernel(
    const float* __restrict__ style,
    const float* __restrict__ weight,
    const float* __restrict__ mod_w,
    const float* __restrict__ mod_b,
    __bf16* __restrict__ wt)
{
    const int b = blockIdx.x;
    const int t = threadIdx.x;

    __shared__ float s_lds[IN_C];
    __shared__ float demod_lds[OUT_C];

    // Phase A: s[c] = dot(style[b,:], mod_w[c,:]) * MOD_SCALE + mod_b[c] + 1
    {
        const float* st = style + b * SDIM;
        const float* mw = mod_w + t * SDIM;
        float dot = 0.f;
        #pragma unroll 4
        for (int j = 0; j < SDIM; j += 4) {
            float4 a = *(const float4*)(st + j);
            float4 w = *(const float4*)(mw + j);
            dot += a.x * w.x + a.y * w.y + a.z * w.z + a.w * w.w;
        }
        s_lds[t] = dot * MOD_SCALE + mod_b[t] + 1.0f;
    }
    __syncthreads();

    // Phase B: demod[o] = 1/sqrt(sum_c (SCALE*weight[c][o]*s[c])^2 + EPS)
    {
        float sum = 0.f;
        #pragma unroll 4
        for (int c = 0; c < IN_C; ++c) {
            float wv = SCALE * weight[c * OUT_C + t] * s_lds[c];
            sum += wv * wv;
        }
        demod_lds[t] = 1.0f / sqrtf(sum + EPS);
    }
    __syncthreads();

    // Phase C: wt[b][o][c] = SCALE*weight[c][o]*s[c]*demod[o].  thread owns c=t
    {
        const float srow = SCALE * s_lds[t];
        __bf16* w_out = wt + b * (IN_C * OUT_C);
        const float* wrow = weight + t * OUT_C;
        #pragma unroll 4
        for (int o = 0; o < OUT_C; o += 4) {
            float4 wv = *(const float4*)(wrow + o);
            w_out[(o + 0) * IN_C + t] = (__bf16)(wv.x * srow * demod_lds[o + 0]);
            w_out[(o + 1) * IN_C + t] = (__bf16)(wv.y * srow * demod_lds[o + 1]);
            w_out[(o + 2) * IN_C + t] = (__bf16)(wv.z * srow * demod_lds[o + 2]);
            w_out[(o + 3) * IN_C + t] = (__bf16)(wv.w * srow * demod_lds[o + 3]);
        }
    }
}

// ---------------------------------------------------------------------------
// Kernel 2: one 128x64 output tile per block. 4 waves split M (wave w owns
// rows w*32..w*32+32); all waves share the 64-col B-slice staged in LDS
// (32 KB, XOR-swizzled: col stride 512B would be a 16-way bank conflict).
// grid = 4 batches * 512 mtiles * 4 ntiles = 8192 blocks, ntile fastest so
// the 4 blocks sharing x-rows run near-simultaneously (L2/L3 hits).
// ---------------------------------------------------------------------------
__global__ __launch_bounds__(256, 4) void gemm_kernel(
    const float* __restrict__ x,
    const __bf16* __restrict__ wt,
    float* __restrict__ out)
{
    const int ntile = blockIdx.x & 3;
    const int mtile = (blockIdx.x >> 2) & 511;
    const int b     = blockIdx.x >> 11;

    const int tid  = threadIdx.x;
    const int lane = tid & 63;
    const int wid  = tid >> 6;
    const int l15  = lane & 15;
    const int kb   = (lane >> 4) * 8;   // k-chunk base within 32-wide k-step

    __shared__ __bf16 blds[64 * IN_C];  // 32 KB

    // Stage B-slice wt[b][ntile*64 .. +64)][:] (contiguous 32 KB), swizzled:
    // 16B chunk index c at row o=c>>5 goes to slot c ^ (o&7)  (byte ^= (o&7)<<4)
    {
        const float4* src = (const float4*)(wt + (size_t)b * (IN_C * OUT_C)
                                               + (size_t)ntile * 64 * IN_C);
        float4* dst = (float4*)blds;
        #pragma unroll
        for (int i = 0; i < 8; ++i) {
            int chunk = tid + i * 256;                // 2048 chunks total
            dst[chunk ^ ((chunk >> 5) & 7)] = src[chunk];
        }
    }
    __syncthreads();

    const float* xbase = x + ((size_t)b * NROWS + (size_t)mtile * 128 + wid * 32 + l15) * IN_C + kb;

    f32x4 acc[2][4] = {};

    #pragma unroll
    for (int ks = 0; ks < 8; ++ks) {
        bf16x8 a[2];
        #pragma unroll
        for (int ms = 0; ms < 2; ++ms) {
            const float* xr = xbase + ms * 16 * IN_C + ks * 32;
            float4 f0 = *(const float4*)(xr);
            float4 f1 = *(const float4*)(xr + 4);
            a[ms][0] = (__bf16)f0.x; a[ms][1] = (__bf16)f0.y;
            a[ms][2] = (__bf16)f0.z; a[ms][3] = (__bf16)f0.w;
            a[ms][4] = (__bf16)f1.x; a[ms][5] = (__bf16)f1.y;
            a[ms][6] = (__bf16)f1.z; a[ms][7] = (__bf16)f1.w;
        }
        #pragma unroll
        for (int nt = 0; nt < 4; ++nt) {
            // col = nt*16 + l15 ; chunk = col*32 + ks*4 + kb/8, swizzled by col&7
            int chunk = ((nt * 16 + l15) << 5) + (ks << 2) + (kb >> 3);
            bf16x8 bf = *(const bf16x8*)(blds + (size_t)(chunk ^ (l15 & 7)) * 8);
            acc[0][nt] = __builtin_amdgcn_mfma_f32_16x16x32_bf16(a[0], bf, acc[0][nt], 0, 0, 0);
            acc[1][nt] = __builtin_amdgcn_mfma_f32_16x16x32_bf16(a[1], bf, acc[1][nt], 0, 0, 0);
        }
    }

    // Store: D lane mapping col = l15, row = (lane>>4)*4 + r
    const int r0 = (lane >> 4) * 4;
    float* obase = out + ((size_t)b * NROWS + (size_t)mtile * 128 + wid * 32) * OUT_C
                       + ntile * 64;
    #pragma unroll
    for (int ms = 0; ms < 2; ++ms) {
        #pragma unroll
        for (int nt = 0; nt < 4; ++nt) {
            float* orow = obase + (size_t)(ms * 16 + r0) * OUT_C + nt * 16 + l15;
            #pragma unroll
            for (int r = 0; r < 4; ++r)
                orow[(size_t)r * OUT_C] = acc[ms][nt][r];
        }
    }
}

extern "C" void kernel_launch(void* const* d_in, const int* in_sizes, int n_in,
                              void* d_out, int out_size, void* d_ws, size_t ws_size,
                              hipStream_t stream) {
    const float* x      = (const float*)d_in[0];
    const float* style  = (const float*)d_in[1];
    const float* weight = (const float*)d_in[2];
    const float* mod_w  = (const float*)d_in[3];
    const float* mod_b  = (const float*)d_in[4];
    float* out = (float*)d_out;
    __bf16* wt = (__bf16*)d_ws;   // 4*256*256 bf16 = 512 KB

    modw_kernel<<<4, 256, 0, stream>>>(style, weight, mod_w, mod_b, wt);
    gemm_kernel<<<8192, 256, 0, stream>>>(x, wt, out);
}